// Round 16
// baseline (304.703 us; speedup 1.0000x reference)
//
#include <hip/hip_runtime.h>
#include <hip/hip_bf16.h>
#include <hip/hip_fp16.h>
#include <math.h>

// ---------------------------------------------------------------------------
// GCN 3-layer + mean-pool + linear head + softmax, fp32 in/out.
// Padded-bucket adjacency (64 slots/node, self-loop slot 0):
//   k_count:     PURE atomic count (saturates memory-side atomic units, 67us)
//   k_fillgemm1: fill (computed-address writes) ∥ layer-1 GEMM (fp32 feats
//                direct, dinv=rsqrt(cnt+1) folded into store; cnt final)
// Gathers: 8 groups x 8 lanes x 16B loads, bucket meta hoisted to registers
// (predicated coalesced load + __shfl). Pool of layer k rides in gemm k+1.
// fp16 pipeline, MFMA v_mfma_f32_16x16x32_f16, fp32 accum.
// ---------------------------------------------------------------------------

#define F 64
#define NGRAPHS 128
#define NCLASSES 10
#define FCAT 192
#define PSPLIT 16
#define CAP 64            // slots per node (deg+1; Poisson(16) -> safe)

typedef _Float16 f16x8 __attribute__((ext_vector_type(8)));
typedef float f32x4 __attribute__((ext_vector_type(4)));

// ---- prep: cnt=0, self-loop meta, W->Wt fp16 transposed -------------------
__global__ void k_prep(const float* __restrict__ W1, const float* __restrict__ W2,
                       const float* __restrict__ W3,
                       int* __restrict__ cnt, int* __restrict__ meta,
                       __half* __restrict__ Wt, int n) {
    int tid = blockIdx.x * blockDim.x + threadIdx.x;
    int stride = gridDim.x * blockDim.x;
    for (int i = tid; i < n; i += stride) {
        cnt[i] = 0;
        meta[(size_t)i << 6] = i;          // self-loop at slot 0
    }
    for (int t = tid; t < 3 * 4096; t += stride) {
        int w = t >> 12, idx = t & 4095;
        int c = idx >> 6, k = idx & 63;
        const float* W = (w == 0) ? W1 : (w == 1) ? W2 : W3;
        Wt[t] = __float2half(W[k * F + c]);
    }
}

// ---- pure atomic count: slot[e] = within-dest order -----------------------
__global__ __launch_bounds__(256) void k_count(const int* __restrict__ col,
                                               int* __restrict__ cnt,
                                               int* __restrict__ slot, int E) {
    int e = blockIdx.x * 256 + threadIdx.x;
    if (e < E) slot[e] = atomicAdd(&cnt[col[e]], 1);
}

// ---- fill ∥ layer-1 GEMM (scaled), modulo-interleaved ---------------------
// blocks with b%5==4 && b/5<gT run a gemm tile; others fill: cidx = b - b/5.
__global__ __launch_bounds__(256) void k_fillgemm1(
        const int* __restrict__ row, const int* __restrict__ col,
        const int* __restrict__ slot, int E, int* __restrict__ meta,
        const float* __restrict__ features, const __half* __restrict__ Wt,
        const int* __restrict__ cnt, __half* __restrict__ xwh, int n, int gT) {
    int k5 = blockIdx.x / 5, r5 = blockIdx.x % 5;
    if (!(r5 == 4 && k5 < gT)) {
        int cidx = blockIdx.x - min(k5, gT);
        int e = cidx * 256 + threadIdx.x;
        if (e < E) meta[((size_t)col[e] << 6) + 1 + slot[e]] = row[e];
        return;
    }
    // layer-1 GEMM tile (16 rows), fp32 features -> fp16 frags, scaled store
    int wid = (int)((k5 * 256 + threadIdx.x) >> 6);
    int lane = threadIdx.x & 63;
    int r0 = wid * 16;
    if (r0 >= n) return;
    int rA = min(r0 + (lane & 15), n - 1);
    int kOff = (lane >> 4) * 8;
    const float4* xp = (const float4*)(features + (size_t)rA * F + kOff);
    float4 fa = xp[0], fb = xp[1];
    float4 fc = xp[8], fd = xp[9];
    f16x8 a0 = {(_Float16)fa.x, (_Float16)fa.y, (_Float16)fa.z, (_Float16)fa.w,
                (_Float16)fb.x, (_Float16)fb.y, (_Float16)fb.z, (_Float16)fb.w};
    f16x8 a1 = {(_Float16)fc.x, (_Float16)fc.y, (_Float16)fc.z, (_Float16)fc.w,
                (_Float16)fd.x, (_Float16)fd.y, (_Float16)fd.z, (_Float16)fd.w};
    f32x4 acc0, acc1, acc2, acc3;
#define DO_CT(CT, ACC) { \
        const f16x8* bp = (const f16x8*)(Wt + (((CT) * 16 + (lane & 15)) << 6) + kOff); \
        f16x8 b0 = bp[0], b1 = bp[4]; \
        f32x4 c = {0.f, 0.f, 0.f, 0.f}; \
        c = __builtin_amdgcn_mfma_f32_16x16x32_f16(a0, b0, c, 0, 0, 0); \
        c = __builtin_amdgcn_mfma_f32_16x16x32_f16(a1, b1, c, 0, 0, 0); \
        ACC = c; }
    DO_CT(0, acc0) DO_CT(1, acc1) DO_CT(2, acc2) DO_CT(3, acc3)
#undef DO_CT
    int rBase = r0 + ((lane >> 4) << 2);
    int q0 = min(rBase + 0, n - 1), q1 = min(rBase + 1, n - 1);
    int q2 = min(rBase + 2, n - 1), q3 = min(rBase + 3, n - 1);
    float d0 = rsqrtf((float)(cnt[q0] + 1));
    float d1 = rsqrtf((float)(cnt[q1] + 1));
    float d2 = rsqrtf((float)(cnt[q2] + 1));
    float d3 = rsqrtf((float)(cnt[q3] + 1));
    int cl = lane & 15;
#define ST_CT(CT, ACC) { \
        __half* op = xwh + (size_t)rBase * F + (CT) * 16 + cl; \
        if (rBase + 0 < n) op[0 * F] = __float2half(ACC.x * d0); \
        if (rBase + 1 < n) op[1 * F] = __float2half(ACC.y * d1); \
        if (rBase + 2 < n) op[2 * F] = __float2half(ACC.z * d2); \
        if (rBase + 3 < n) op[3 * F] = __float2half(ACC.w * d3); }
    ST_CT(0, acc0) ST_CT(1, acc1) ST_CT(2, acc2) ST_CT(3, acc3)
#undef ST_CT
}

// ---- gemm (layers 2,3) with pool of the PREVIOUS layer riding along -------
__global__ __launch_bounds__(256) void k_gemmpool(
        const __half* __restrict__ xh, const __half* __restrict__ Wt,
        const int* __restrict__ cnt, __half* __restrict__ xwh, int n,
        int gemmBlocks,
        const __half* __restrict__ poolSrc, const int* __restrict__ batch,
        float* __restrict__ pooledPart, int layerOff) {
    if (blockIdx.x >= gemmBlocks) {
        int b = blockIdx.x - gemmBlocks;
        int g = b >> 4, part = b & 15;
        int lo = 0, hi = n;
        while (lo < hi) { int m = (lo + hi) >> 1; if (batch[m] < g) lo = m + 1; else hi = m; }
        int s0 = lo;
        lo = s0; hi = n;
        while (lo < hi) { int m = (lo + hi) >> 1; if (batch[m] < g + 1) lo = m + 1; else hi = m; }
        int e0 = lo;
        int len = e0 - s0;
        int chunk = (len + PSPLIT - 1) / PSPLIT;
        int r0 = s0 + part * chunk;
        int r1 = min(r0 + chunk, e0);
        __shared__ float red[256];
        int f = threadIdx.x & 63, sub = threadIdx.x >> 6;
        float s = 0.0f;
        for (int i = r0 + sub; i < r1; i += 4)
            s += __half2float(poolSrc[(size_t)i * F + f]);
        red[threadIdx.x] = s;
        __syncthreads();
        if (threadIdx.x < 64) {
            float t = red[f] + red[f + 64] + red[f + 128] + red[f + 192];
            pooledPart[(size_t)(part * NGRAPHS + g) * FCAT + layerOff + f] = t;
        }
        return;
    }
    int wid = (int)((blockIdx.x * 256 + threadIdx.x) >> 6);
    int lane = threadIdx.x & 63;
    int r0 = wid * 16;
    if (r0 >= n) return;
    int rA = min(r0 + (lane & 15), n - 1);
    int kOff = (lane >> 4) * 8;
    const f16x8* ap = (const f16x8*)(xh + (size_t)rA * F + kOff);
    f16x8 a0 = ap[0];
    f16x8 a1 = ap[4];
    f32x4 acc0, acc1, acc2, acc3;
#define DO_CT(CT, ACC) { \
        const f16x8* bp = (const f16x8*)(Wt + (((CT) * 16 + (lane & 15)) << 6) + kOff); \
        f16x8 b0 = bp[0], b1 = bp[4]; \
        f32x4 c = {0.f, 0.f, 0.f, 0.f}; \
        c = __builtin_amdgcn_mfma_f32_16x16x32_f16(a0, b0, c, 0, 0, 0); \
        c = __builtin_amdgcn_mfma_f32_16x16x32_f16(a1, b1, c, 0, 0, 0); \
        ACC = c; }
    DO_CT(0, acc0) DO_CT(1, acc1) DO_CT(2, acc2) DO_CT(3, acc3)
#undef DO_CT
    int rBase = r0 + ((lane >> 4) << 2);
    int q0 = min(rBase + 0, n - 1), q1 = min(rBase + 1, n - 1);
    int q2 = min(rBase + 2, n - 1), q3 = min(rBase + 3, n - 1);
    float d0 = rsqrtf((float)(cnt[q0] + 1));
    float d1 = rsqrtf((float)(cnt[q1] + 1));
    float d2 = rsqrtf((float)(cnt[q2] + 1));
    float d3 = rsqrtf((float)(cnt[q3] + 1));
    int cl = lane & 15;
#define ST_CT(CT, ACC) { \
        __half* op = xwh + (size_t)rBase * F + (CT) * 16 + cl; \
        if (rBase + 0 < n) op[0 * F] = __float2half(ACC.x * d0); \
        if (rBase + 1 < n) op[1 * F] = __float2half(ACC.y * d1); \
        if (rBase + 2 < n) op[2 * F] = __float2half(ACC.z * d2); \
        if (rBase + 3 < n) op[3 * F] = __float2half(ACC.w * d3); }
    ST_CT(0, acc0) ST_CT(1, acc1) ST_CT(2, acc2) ST_CT(3, acc3)
#undef ST_CT
}

// ---- standalone pool (layer 3) --------------------------------------------
__global__ __launch_bounds__(256) void k_pool(const __half* __restrict__ src,
                                              const int* __restrict__ batch, int n,
                                              float* __restrict__ pooledPart,
                                              int layerOff) {
    int g = blockIdx.x >> 4, part = blockIdx.x & 15;
    int lo = 0, hi = n;
    while (lo < hi) { int m = (lo + hi) >> 1; if (batch[m] < g) lo = m + 1; else hi = m; }
    int s0 = lo;
    lo = s0; hi = n;
    while (lo < hi) { int m = (lo + hi) >> 1; if (batch[m] < g + 1) lo = m + 1; else hi = m; }
    int e0 = lo;
    int len = e0 - s0;
    int chunk = (len + PSPLIT - 1) / PSPLIT;
    int r0 = s0 + part * chunk;
    int r1 = min(r0 + chunk, e0);
    __shared__ float red[256];
    int f = threadIdx.x & 63, sub = threadIdx.x >> 6;
    float s = 0.0f;
    for (int i = r0 + sub; i < r1; i += 4)
        s += __half2float(src[(size_t)i * F + f]);
    red[threadIdx.x] = s;
    __syncthreads();
    if (threadIdx.x < 64) {
        float t = red[f] + red[f + 64] + red[f + 128] + red[f + 192];
        pooledPart[(size_t)(part * NGRAPHS + g) * FCAT + layerOff + f] = t;
    }
}

// out[v] = relu( dinv[v] * sum_{r in bucket[v]} xw'[r] + b ), fp16 out.
// 8 groups x 8 lanes x 16B loads; meta hoisted (predicated) + __shfl.
__global__ __launch_bounds__(256) void k_gather(const __half* __restrict__ xwh,
                                                const int* __restrict__ meta,
                                                const int* __restrict__ cnt,
                                                const float* __restrict__ bias,
                                                __half* __restrict__ out, int n) {
    int wid = (int)((blockIdx.x * blockDim.x + threadIdx.x) >> 6);
    if (wid >= n) return;
    int lane = threadIdx.x & 63;
    int g = lane >> 3, s = lane & 7;
    int cv = cnt[wid] + 1;               // deg + self
    size_t base = (size_t)wid << 6;
    int myMeta = (lane < cv) ? meta[base + lane] : 0;
    float a0 = 0.f, a1 = 0.f, a2 = 0.f, a3 = 0.f;
    float a4 = 0.f, a5 = 0.f, a6 = 0.f, a7 = 0.f;
    for (int i = g; i < cv; i += 8) {
        int r = __shfl(myMeta, i);
        uint4 v = *((const uint4*)(xwh + ((size_t)r << 6)) + s);
        __half2 h0 = *reinterpret_cast<const __half2*>(&v.x);
        __half2 h1 = *reinterpret_cast<const __half2*>(&v.y);
        __half2 h2 = *reinterpret_cast<const __half2*>(&v.z);
        __half2 h3 = *reinterpret_cast<const __half2*>(&v.w);
        float2 f;
        f = __half22float2(h0); a0 += f.x; a1 += f.y;
        f = __half22float2(h1); a2 += f.x; a3 += f.y;
        f = __half22float2(h2); a4 += f.x; a5 += f.y;
        f = __half22float2(h3); a6 += f.x; a7 += f.y;
    }
#pragma unroll
    for (int m = 8; m <= 32; m <<= 1) {
        a0 += __shfl_xor(a0, m); a1 += __shfl_xor(a1, m);
        a2 += __shfl_xor(a2, m); a3 += __shfl_xor(a3, m);
        a4 += __shfl_xor(a4, m); a5 += __shfl_xor(a5, m);
        a6 += __shfl_xor(a6, m); a7 += __shfl_xor(a7, m);
    }
    if (g == 0) {
        float dc = rsqrtf((float)cv);
        float4 bv0 = ((const float4*)bias)[2 * s];
        float4 bv1 = ((const float4*)bias)[2 * s + 1];
        __half2 o0 = __floats2half2_rn(fmaxf(fmaf(a0, dc, bv0.x), 0.f),
                                       fmaxf(fmaf(a1, dc, bv0.y), 0.f));
        __half2 o1 = __floats2half2_rn(fmaxf(fmaf(a2, dc, bv0.z), 0.f),
                                       fmaxf(fmaf(a3, dc, bv0.w), 0.f));
        __half2 o2 = __floats2half2_rn(fmaxf(fmaf(a4, dc, bv1.x), 0.f),
                                       fmaxf(fmaf(a5, dc, bv1.y), 0.f));
        __half2 o3 = __floats2half2_rn(fmaxf(fmaf(a6, dc, bv1.z), 0.f),
                                       fmaxf(fmaf(a7, dc, bv1.w), 0.f));
        uint4 pk;
        pk.x = *reinterpret_cast<unsigned int*>(&o0);
        pk.y = *reinterpret_cast<unsigned int*>(&o1);
        pk.z = *reinterpret_cast<unsigned int*>(&o2);
        pk.w = *reinterpret_cast<unsigned int*>(&o3);
        *((uint4*)(out + base) + s) = pk;
    }
}

// one block per graph: reduce 16 partials -> pooled (LDS), logits, softmax
__global__ __launch_bounds__(192) void k_head(const float* __restrict__ pooledPart,
                                              const int* __restrict__ batch, int n,
                                              const float* __restrict__ Wf,
                                              const float* __restrict__ bf,
                                              float* __restrict__ out) {
    int g = blockIdx.x;
    __shared__ float pool[FCAT];
    __shared__ float lg[NCLASSES];
    int f = threadIdx.x;
    float s = 0.0f;
#pragma unroll
    for (int p = 0; p < PSPLIT; ++p)
        s += pooledPart[(size_t)(p * NGRAPHS + g) * FCAT + f];
    int lo = 0, hi = n;
    while (lo < hi) { int m = (lo + hi) >> 1; if (batch[m] < g) lo = m + 1; else hi = m; }
    int s0 = lo;
    lo = s0; hi = n;
    while (lo < hi) { int m = (lo + hi) >> 1; if (batch[m] < g + 1) lo = m + 1; else hi = m; }
    float invc = 1.0f / fmaxf((float)(lo - s0), 1.0f);
    pool[f] = s * invc;
    __syncthreads();
    if (f < NCLASSES) {
        float acc = bf[f];
        for (int k = 0; k < FCAT; ++k) acc = fmaf(pool[k], Wf[k * NCLASSES + f], acc);
        lg[f] = acc;
    }
    __syncthreads();
    if (f == 0) {
        float mx = lg[0];
#pragma unroll
        for (int c = 1; c < NCLASSES; ++c) mx = fmaxf(mx, lg[c]);
        float ss = 0.0f;
        float e[NCLASSES];
#pragma unroll
        for (int c = 0; c < NCLASSES; ++c) { e[c] = expf(lg[c] - mx); ss += e[c]; }
        float inv = 1.0f / ss;
#pragma unroll
        for (int c = 0; c < NCLASSES; ++c) out[g * NCLASSES + c] = e[c] * inv;
    }
}

// ---------------------------------------------------------------------------

extern "C" void kernel_launch(void* const* d_in, const int* in_sizes, int n_in,
                              void* d_out, int out_size, void* d_ws, size_t ws_size,
                              hipStream_t stream) {
    const float* features = (const float*)d_in[0];
    const int*   edge     = (const int*)d_in[1];
    const int*   batch    = (const int*)d_in[2];
    const float* W1 = (const float*)d_in[3]; const float* b1 = (const float*)d_in[4];
    const float* W2 = (const float*)d_in[5]; const float* b2 = (const float*)d_in[6];
    const float* W3 = (const float*)d_in[7]; const float* b3 = (const float*)d_in[8];
    const float* Wf = (const float*)d_in[9]; const float* bf = (const float*)d_in[10];
    float* out = (float*)d_out;

    const int n = in_sizes[0] / F;   // 100000
    const int E = in_sizes[1] / 2;   // 1600000
    const int* row = edge;
    const int* col = edge + E;

    // workspace layout
    __half* x0h   = (__half*)d_ws;                     // [n*64] layer3 out
    __half* bufAh = x0h + (size_t)n * F;               // [n*64] layer1 out
    __half* bufBh = bufAh + (size_t)n * F;             // [n*64] layer2 out
    __half* xwh   = bufBh + (size_t)n * F;             // [n*64]
    __half* Wt    = xwh + (size_t)n * F;               // [3*64*64]
    int*    meta  = (int*)(Wt + 3 * F * F);            // [n*CAP]
    int*    slot  = meta + (size_t)n * CAP;            // [E]
    int*    cnt   = slot + E;                          // [n]
    float*  pooledPart = (float*)(cnt + n);            // [16*128*192]

    const int BT = 256;
    int gE  = (E + BT - 1) / BT;           // 6250 count/fill blocks
    int gW  = (n + 3) / 4;                 // gather grid (4 nodes/block)
    int gT  = ((n + 15) / 16 + 3) / 4;     // gemm grid (4 tiles/block)
    const int PB = NGRAPHS * PSPLIT;       // 2048 pool blocks

    // ---- build ----
    k_prep<<<256, BT, 0, stream>>>(W1, W2, W3, cnt, meta, Wt, n);
    k_count<<<gE, BT, 0, stream>>>(col, cnt, slot, E);
    k_fillgemm1<<<gE + gT, BT, 0, stream>>>(row, col, slot, E, meta,
                                            features, Wt, cnt, xwh, n, gT);

    // ---- layer 1 gather ----
    k_gather<<<gW, BT, 0, stream>>>(xwh, meta, cnt, b1, bufAh, n);

    // ---- layer 2 gemm ∥ pool(layer1) ----
    k_gemmpool<<<gT + PB, BT, 0, stream>>>(bufAh, Wt + 4096, cnt, xwh, n, gT,
                                           bufAh, batch, pooledPart, 0);
    k_gather<<<gW, BT, 0, stream>>>(xwh, meta, cnt, b2, bufBh, n);

    // ---- layer 3 gemm ∥ pool(layer2) ----
    k_gemmpool<<<gT + PB, BT, 0, stream>>>(bufBh, Wt + 8192, cnt, xwh, n, gT,
                                           bufBh, batch, pooledPart, F);
    k_gather<<<gW, BT, 0, stream>>>(xwh, meta, cnt, b3, x0h, n);

    // ---- pool(layer3) + head ----
    k_pool<<<PB, BT, 0, stream>>>(x0h, batch, n, pooledPart, 2 * F);
    k_head<<<NGRAPHS, FCAT, 0, stream>>>(pooledPart, batch, n, Wf, bf, out);
}

// Round 17
// 291.674 us; speedup vs baseline: 1.0447x; 1.0447x over previous
//
#include <hip/hip_runtime.h>
#include <hip/hip_bf16.h>
#include <hip/hip_fp16.h>
#include <math.h>

// ---------------------------------------------------------------------------
// GCN 3-layer + mean-pool + linear head + softmax, fp32 in/out.
// Padded-bucket adjacency (64 slots/node, NO self slot — gather adds the
// self row directly). Build is ONE fused pass:
//   k_cfg1: count+fill (ILP-4: int4 edge loads, 4 independent atomics, then
//           4 meta stores) ∥ layer-1 GEMM (LDS-staged W1, unscaled store),
//           1:1 modulo-interleaved blocks.
// gather1 applies per-edge dinv=rsqrt(cnt+1) via a register-hoisted dr table
// (one load/lane + __shfl); layers 2/3 fold dinv into the GEMM store.
// Gathers: 8 groups x 8 lanes x 16B loads. Pool of layer k rides in gemm k+1.
// fp16 pipeline, MFMA v_mfma_f32_16x16x32_f16, fp32 accum.
// ---------------------------------------------------------------------------

#define F 64
#define NGRAPHS 128
#define NCLASSES 10
#define FCAT 192
#define PSPLIT 16
#define CAP 64            // slots per node (deg; Poisson(16) -> safe)

typedef _Float16 f16x8 __attribute__((ext_vector_type(8)));
typedef float f32x4 __attribute__((ext_vector_type(4)));

// ---- prep: cnt=0, W->Wt fp16 transposed (layers 2,3 use Wt) ---------------
__global__ void k_prep(const float* __restrict__ W1, const float* __restrict__ W2,
                       const float* __restrict__ W3,
                       int* __restrict__ cnt, __half* __restrict__ Wt, int n) {
    int tid = blockIdx.x * blockDim.x + threadIdx.x;
    int stride = gridDim.x * blockDim.x;
    for (int i = tid; i < n; i += stride) cnt[i] = 0;
    for (int t = tid; t < 3 * 4096; t += stride) {
        int w = t >> 12, idx = t & 4095;
        int c = idx >> 6, k = idx & 63;
        const float* W = (w == 0) ? W1 : (w == 1) ? W2 : W3;
        Wt[t] = __float2half(W[k * F + c]);
    }
}

// ---- fused count+fill (ILP-4) ∥ layer-1 GEMM (LDS W1), 1:1 interleave -----
__global__ __launch_bounds__(256) void k_cfg1(
        const int* __restrict__ row, const int* __restrict__ col,
        int* __restrict__ cnt, int* __restrict__ meta, int E,
        const float* __restrict__ W1, const float* __restrict__ features,
        __half* __restrict__ xwh, int n, int cfB, int gT) {
    int half = blockIdx.x >> 1;
    if ((blockIdx.x & 1) == 0) {
        // ---- count+fill: 4 edges/thread, independent atomics then stores
        if (half >= cfB) return;
        int e0 = (half * 256 + threadIdx.x) * 4;
        if (e0 + 3 < E) {
            int4 c4 = *(const int4*)(col + e0);
            int4 r4 = *(const int4*)(row + e0);
            int s0 = atomicAdd(&cnt[c4.x], 1);
            int s1 = atomicAdd(&cnt[c4.y], 1);
            int s2 = atomicAdd(&cnt[c4.z], 1);
            int s3 = atomicAdd(&cnt[c4.w], 1);
            meta[((size_t)c4.x << 6) + s0] = r4.x;
            meta[((size_t)c4.y << 6) + s1] = r4.y;
            meta[((size_t)c4.z << 6) + s2] = r4.z;
            meta[((size_t)c4.w << 6) + s3] = r4.w;
        } else {
            for (int e = e0; e < E; ++e) {
                int c = col[e];
                int s = atomicAdd(&cnt[c], 1);
                meta[((size_t)c << 6) + s] = row[e];
            }
        }
        return;
    }
    // ---- layer-1 GEMM tile (16 rows), fp32 feats, LDS-staged W1, UNSCALED
    if (half >= gT) return;
    __shared__ __half Wl[64 * 72];          // [c][72] padded (2-way banks)
    for (int i = threadIdx.x; i < 4096; i += 256) {
        int k = i >> 6, c = i & 63;
        Wl[c * 72 + k] = __float2half(W1[i]);
    }
    __syncthreads();
    int wid = (int)((half * 256 + threadIdx.x) >> 6);
    int lane = threadIdx.x & 63;
    int r0 = wid * 16;
    if (r0 >= n) return;
    int rA = min(r0 + (lane & 15), n - 1);
    int kOff = (lane >> 4) * 8;
    const float4* xp = (const float4*)(features + (size_t)rA * F + kOff);
    float4 fa = xp[0], fb = xp[1];
    float4 fc = xp[8], fd = xp[9];
    f16x8 a0 = {(_Float16)fa.x, (_Float16)fa.y, (_Float16)fa.z, (_Float16)fa.w,
                (_Float16)fb.x, (_Float16)fb.y, (_Float16)fb.z, (_Float16)fb.w};
    f16x8 a1 = {(_Float16)fc.x, (_Float16)fc.y, (_Float16)fc.z, (_Float16)fc.w,
                (_Float16)fd.x, (_Float16)fd.y, (_Float16)fd.z, (_Float16)fd.w};
    f32x4 acc0, acc1, acc2, acc3;
#define DO_CT(CT, ACC) { \
        const __half* bb = Wl + ((CT) * 16 + (lane & 15)) * 72 + kOff; \
        f16x8 b0 = *(const f16x8*)bb; \
        f16x8 b1 = *(const f16x8*)(bb + 32); \
        f32x4 c = {0.f, 0.f, 0.f, 0.f}; \
        c = __builtin_amdgcn_mfma_f32_16x16x32_f16(a0, b0, c, 0, 0, 0); \
        c = __builtin_amdgcn_mfma_f32_16x16x32_f16(a1, b1, c, 0, 0, 0); \
        ACC = c; }
    DO_CT(0, acc0) DO_CT(1, acc1) DO_CT(2, acc2) DO_CT(3, acc3)
#undef DO_CT
    int rBase = r0 + ((lane >> 4) << 2);
    int cl = lane & 15;
#define ST_CT(CT, ACC) { \
        __half* op = xwh + (size_t)rBase * F + (CT) * 16 + cl; \
        if (rBase + 0 < n) op[0 * F] = __float2half(ACC.x); \
        if (rBase + 1 < n) op[1 * F] = __float2half(ACC.y); \
        if (rBase + 2 < n) op[2 * F] = __float2half(ACC.z); \
        if (rBase + 3 < n) op[3 * F] = __float2half(ACC.w); }
    ST_CT(0, acc0) ST_CT(1, acc1) ST_CT(2, acc2) ST_CT(3, acc3)
#undef ST_CT
}

// ---- gemm (layers 2,3) with pool of the PREVIOUS layer riding along -------
__global__ __launch_bounds__(256) void k_gemmpool(
        const __half* __restrict__ xh, const __half* __restrict__ Wt,
        const int* __restrict__ cnt, __half* __restrict__ xwh, int n,
        int gemmBlocks,
        const __half* __restrict__ poolSrc, const int* __restrict__ batch,
        float* __restrict__ pooledPart, int layerOff) {
    if (blockIdx.x >= gemmBlocks) {
        int b = blockIdx.x - gemmBlocks;
        int g = b >> 4, part = b & 15;
        int lo = 0, hi = n;
        while (lo < hi) { int m = (lo + hi) >> 1; if (batch[m] < g) lo = m + 1; else hi = m; }
        int s0 = lo;
        lo = s0; hi = n;
        while (lo < hi) { int m = (lo + hi) >> 1; if (batch[m] < g + 1) lo = m + 1; else hi = m; }
        int e0 = lo;
        int len = e0 - s0;
        int chunk = (len + PSPLIT - 1) / PSPLIT;
        int r0 = s0 + part * chunk;
        int r1 = min(r0 + chunk, e0);
        __shared__ float red[256];
        int f = threadIdx.x & 63, sub = threadIdx.x >> 6;
        float s = 0.0f;
        for (int i = r0 + sub; i < r1; i += 4)
            s += __half2float(poolSrc[(size_t)i * F + f]);
        red[threadIdx.x] = s;
        __syncthreads();
        if (threadIdx.x < 64) {
            float t = red[f] + red[f + 64] + red[f + 128] + red[f + 192];
            pooledPart[(size_t)(part * NGRAPHS + g) * FCAT + layerOff + f] = t;
        }
        return;
    }
    int wid = (int)((blockIdx.x * 256 + threadIdx.x) >> 6);
    int lane = threadIdx.x & 63;
    int r0 = wid * 16;
    if (r0 >= n) return;
    int rA = min(r0 + (lane & 15), n - 1);
    int kOff = (lane >> 4) * 8;
    const f16x8* ap = (const f16x8*)(xh + (size_t)rA * F + kOff);
    f16x8 a0 = ap[0];
    f16x8 a1 = ap[4];
    f32x4 acc0, acc1, acc2, acc3;
#define DO_CT(CT, ACC) { \
        const f16x8* bp = (const f16x8*)(Wt + (((CT) * 16 + (lane & 15)) << 6) + kOff); \
        f16x8 b0 = bp[0], b1 = bp[4]; \
        f32x4 c = {0.f, 0.f, 0.f, 0.f}; \
        c = __builtin_amdgcn_mfma_f32_16x16x32_f16(a0, b0, c, 0, 0, 0); \
        c = __builtin_amdgcn_mfma_f32_16x16x32_f16(a1, b1, c, 0, 0, 0); \
        ACC = c; }
    DO_CT(0, acc0) DO_CT(1, acc1) DO_CT(2, acc2) DO_CT(3, acc3)
#undef DO_CT
    int rBase = r0 + ((lane >> 4) << 2);
    int q0 = min(rBase + 0, n - 1), q1 = min(rBase + 1, n - 1);
    int q2 = min(rBase + 2, n - 1), q3 = min(rBase + 3, n - 1);
    float d0 = rsqrtf((float)(cnt[q0] + 1));
    float d1 = rsqrtf((float)(cnt[q1] + 1));
    float d2 = rsqrtf((float)(cnt[q2] + 1));
    float d3 = rsqrtf((float)(cnt[q3] + 1));
    int cl = lane & 15;
#define ST_CT(CT, ACC) { \
        __half* op = xwh + (size_t)rBase * F + (CT) * 16 + cl; \
        if (rBase + 0 < n) op[0 * F] = __float2half(ACC.x * d0); \
        if (rBase + 1 < n) op[1 * F] = __float2half(ACC.y * d1); \
        if (rBase + 2 < n) op[2 * F] = __float2half(ACC.z * d2); \
        if (rBase + 3 < n) op[3 * F] = __float2half(ACC.w * d3); }
    ST_CT(0, acc0) ST_CT(1, acc1) ST_CT(2, acc2) ST_CT(3, acc3)
#undef ST_CT
}

// ---- standalone pool (layer 3) --------------------------------------------
__global__ __launch_bounds__(256) void k_pool(const __half* __restrict__ src,
                                              const int* __restrict__ batch, int n,
                                              float* __restrict__ pooledPart,
                                              int layerOff) {
    int g = blockIdx.x >> 4, part = blockIdx.x & 15;
    int lo = 0, hi = n;
    while (lo < hi) { int m = (lo + hi) >> 1; if (batch[m] < g) lo = m + 1; else hi = m; }
    int s0 = lo;
    lo = s0; hi = n;
    while (lo < hi) { int m = (lo + hi) >> 1; if (batch[m] < g + 1) lo = m + 1; else hi = m; }
    int e0 = lo;
    int len = e0 - s0;
    int chunk = (len + PSPLIT - 1) / PSPLIT;
    int r0 = s0 + part * chunk;
    int r1 = min(r0 + chunk, e0);
    __shared__ float red[256];
    int f = threadIdx.x & 63, sub = threadIdx.x >> 6;
    float s = 0.0f;
    for (int i = r0 + sub; i < r1; i += 4)
        s += __half2float(src[(size_t)i * F + f]);
    red[threadIdx.x] = s;
    __syncthreads();
    if (threadIdx.x < 64) {
        float t = red[f] + red[f + 64] + red[f + 128] + red[f + 192];
        pooledPart[(size_t)(part * NGRAPHS + g) * FCAT + layerOff + f] = t;
    }
}

// out[v] = relu( dinv[v] * (self + sum_{r in bucket[v]} w_r*xw'[r]) + b ).
// 8 groups x 8 lanes x 16B loads; meta (+dr table if SCALE_SRC) hoisted to
// registers; self row added directly by group 0 (coalesced load, no meta).
template<bool SCALE_SRC>
__global__ __launch_bounds__(256) void k_gather(const __half* __restrict__ xwh,
                                                const int* __restrict__ meta,
                                                const int* __restrict__ cnt,
                                                const float* __restrict__ bias,
                                                __half* __restrict__ out, int n) {
    int wid = (int)((blockIdx.x * blockDim.x + threadIdx.x) >> 6);
    if (wid >= n) return;
    int lane = threadIdx.x & 63;
    int g = lane >> 3, s = lane & 7;
    int deg = cnt[wid];
    float dc = rsqrtf((float)(deg + 1));
    size_t mbase = (size_t)wid << 6;
    int myMeta = (lane < deg) ? meta[mbase + lane] : 0;
    float myDr = 0.0f;
    if (SCALE_SRC) myDr = (lane < deg) ? rsqrtf((float)(cnt[myMeta] + 1)) : 0.0f;
    float a0 = 0.f, a1 = 0.f, a2 = 0.f, a3 = 0.f;
    float a4 = 0.f, a5 = 0.f, a6 = 0.f, a7 = 0.f;
    if (g == 0) {
        // self contribution: dinv[v]*xw[v]; xw unscaled if SCALE_SRC
        uint4 v = *((const uint4*)(xwh + mbase) + s);
        __half2 h0 = *reinterpret_cast<const __half2*>(&v.x);
        __half2 h1 = *reinterpret_cast<const __half2*>(&v.y);
        __half2 h2 = *reinterpret_cast<const __half2*>(&v.z);
        __half2 h3 = *reinterpret_cast<const __half2*>(&v.w);
        float w = SCALE_SRC ? dc : 1.0f;
        float2 f;
        f = __half22float2(h0); a0 = f.x * w; a1 = f.y * w;
        f = __half22float2(h1); a2 = f.x * w; a3 = f.y * w;
        f = __half22float2(h2); a4 = f.x * w; a5 = f.y * w;
        f = __half22float2(h3); a6 = f.x * w; a7 = f.y * w;
    }
    for (int i = g; i < deg; i += 8) {
        int r = __shfl(myMeta, i);
        uint4 v = *((const uint4*)(xwh + ((size_t)r << 6)) + s);
        __half2 h0 = *reinterpret_cast<const __half2*>(&v.x);
        __half2 h1 = *reinterpret_cast<const __half2*>(&v.y);
        __half2 h2 = *reinterpret_cast<const __half2*>(&v.z);
        __half2 h3 = *reinterpret_cast<const __half2*>(&v.w);
        float2 f;
        if (SCALE_SRC) {
            float dr = __shfl(myDr, i);
            f = __half22float2(h0); a0 = fmaf(f.x, dr, a0); a1 = fmaf(f.y, dr, a1);
            f = __half22float2(h1); a2 = fmaf(f.x, dr, a2); a3 = fmaf(f.y, dr, a3);
            f = __half22float2(h2); a4 = fmaf(f.x, dr, a4); a5 = fmaf(f.y, dr, a5);
            f = __half22float2(h3); a6 = fmaf(f.x, dr, a6); a7 = fmaf(f.y, dr, a7);
        } else {
            f = __half22float2(h0); a0 += f.x; a1 += f.y;
            f = __half22float2(h1); a2 += f.x; a3 += f.y;
            f = __half22float2(h2); a4 += f.x; a5 += f.y;
            f = __half22float2(h3); a6 += f.x; a7 += f.y;
        }
    }
#pragma unroll
    for (int m = 8; m <= 32; m <<= 1) {
        a0 += __shfl_xor(a0, m); a1 += __shfl_xor(a1, m);
        a2 += __shfl_xor(a2, m); a3 += __shfl_xor(a3, m);
        a4 += __shfl_xor(a4, m); a5 += __shfl_xor(a5, m);
        a6 += __shfl_xor(a6, m); a7 += __shfl_xor(a7, m);
    }
    if (g == 0) {
        float4 bv0 = ((const float4*)bias)[2 * s];
        float4 bv1 = ((const float4*)bias)[2 * s + 1];
        __half2 o0 = __floats2half2_rn(fmaxf(fmaf(a0, dc, bv0.x), 0.f),
                                       fmaxf(fmaf(a1, dc, bv0.y), 0.f));
        __half2 o1 = __floats2half2_rn(fmaxf(fmaf(a2, dc, bv0.z), 0.f),
                                       fmaxf(fmaf(a3, dc, bv0.w), 0.f));
        __half2 o2 = __floats2half2_rn(fmaxf(fmaf(a4, dc, bv1.x), 0.f),
                                       fmaxf(fmaf(a5, dc, bv1.y), 0.f));
        __half2 o3 = __floats2half2_rn(fmaxf(fmaf(a6, dc, bv1.z), 0.f),
                                       fmaxf(fmaf(a7, dc, bv1.w), 0.f));
        uint4 pk;
        pk.x = *reinterpret_cast<unsigned int*>(&o0);
        pk.y = *reinterpret_cast<unsigned int*>(&o1);
        pk.z = *reinterpret_cast<unsigned int*>(&o2);
        pk.w = *reinterpret_cast<unsigned int*>(&o3);
        *((uint4*)(out + ((size_t)wid << 6)) + s) = pk;
    }
}

// one block per graph: reduce 16 partials -> pooled (LDS), logits, softmax
__global__ __launch_bounds__(192) void k_head(const float* __restrict__ pooledPart,
                                              const int* __restrict__ batch, int n,
                                              const float* __restrict__ Wf,
                                              const float* __restrict__ bf,
                                              float* __restrict__ out) {
    int g = blockIdx.x;
    __shared__ float pool[FCAT];
    __shared__ float lg[NCLASSES];
    int f = threadIdx.x;
    float s = 0.0f;
#pragma unroll
    for (int p = 0; p < PSPLIT; ++p)
        s += pooledPart[(size_t)(p * NGRAPHS + g) * FCAT + f];
    int lo = 0, hi = n;
    while (lo < hi) { int m = (lo + hi) >> 1; if (batch[m] < g) lo = m + 1; else hi = m; }
    int s0 = lo;
    lo = s0; hi = n;
    while (lo < hi) { int m = (lo + hi) >> 1; if (batch[m] < g + 1) lo = m + 1; else hi = m; }
    float invc = 1.0f / fmaxf((float)(lo - s0), 1.0f);
    pool[f] = s * invc;
    __syncthreads();
    if (f < NCLASSES) {
        float acc = bf[f];
        for (int k = 0; k < FCAT; ++k) acc = fmaf(pool[k], Wf[k * NCLASSES + f], acc);
        lg[f] = acc;
    }
    __syncthreads();
    if (f == 0) {
        float mx = lg[0];
#pragma unroll
        for (int c = 1; c < NCLASSES; ++c) mx = fmaxf(mx, lg[c]);
        float ss = 0.0f;
        float e[NCLASSES];
#pragma unroll
        for (int c = 0; c < NCLASSES; ++c) { e[c] = expf(lg[c] - mx); ss += e[c]; }
        float inv = 1.0f / ss;
#pragma unroll
        for (int c = 0; c < NCLASSES; ++c) out[g * NCLASSES + c] = e[c] * inv;
    }
}

// ---------------------------------------------------------------------------

extern "C" void kernel_launch(void* const* d_in, const int* in_sizes, int n_in,
                              void* d_out, int out_size, void* d_ws, size_t ws_size,
                              hipStream_t stream) {
    const float* features = (const float*)d_in[0];
    const int*   edge     = (const int*)d_in[1];
    const int*   batch    = (const int*)d_in[2];
    const float* W1 = (const float*)d_in[3]; const float* b1 = (const float*)d_in[4];
    const float* W2 = (const float*)d_in[5]; const float* b2 = (const float*)d_in[6];
    const float* W3 = (const float*)d_in[7]; const float* b3 = (const float*)d_in[8];
    const float* Wf = (const float*)d_in[9]; const float* bf = (const float*)d_in[10];
    float* out = (float*)d_out;

    const int n = in_sizes[0] / F;   // 100000
    const int E = in_sizes[1] / 2;   // 1600000
    const int* row = edge;
    const int* col = edge + E;

    // workspace layout
    __half* x0h   = (__half*)d_ws;                     // [n*64] layer3 out
    __half* bufAh = x0h + (size_t)n * F;               // [n*64] layer1 out
    __half* bufBh = bufAh + (size_t)n * F;             // [n*64] layer2 out
    __half* xwh   = bufBh + (size_t)n * F;             // [n*64]
    __half* Wt    = xwh + (size_t)n * F;               // [3*64*64]
    int*    meta  = (int*)(Wt + 3 * F * F);            // [n*CAP]
    int*    cnt   = meta + (size_t)n * CAP;            // [n]
    float*  pooledPart = (float*)(cnt + n);            // [16*128*192]

    const int BT = 256;
    int cfB = (E + 1023) / 1024;           // count+fill blocks (4 edges/thread)
    int gW  = (n + 3) / 4;                 // gather grid (4 nodes/block)
    int gT  = ((n + 15) / 16 + 3) / 4;     // gemm grid (4 tiles/block)
    int mx2 = 2 * max(cfB, gT);            // interleaved build grid
    const int PB = NGRAPHS * PSPLIT;       // 2048 pool blocks

    // ---- build: prep, then fused count+fill ∥ layer-1 GEMM ----
    k_prep<<<256, BT, 0, stream>>>(W1, W2, W3, cnt, Wt, n);
    k_cfg1<<<mx2, BT, 0, stream>>>(row, col, cnt, meta, E, W1, features,
                                   xwh, n, cfB, gT);

    // ---- layer 1 gather (per-edge dinv via hoisted table) ----
    k_gather<true><<<gW, BT, 0, stream>>>(xwh, meta, cnt, b1, bufAh, n);

    // ---- layer 2 gemm ∥ pool(layer1) ----
    k_gemmpool<<<gT + PB, BT, 0, stream>>>(bufAh, Wt + 4096, cnt, xwh, n, gT,
                                           bufAh, batch, pooledPart, 0);
    k_gather<false><<<gW, BT, 0, stream>>>(xwh, meta, cnt, b2, bufBh, n);

    // ---- layer 3 gemm ∥ pool(layer2) ----
    k_gemmpool<<<gT + PB, BT, 0, stream>>>(bufBh, Wt + 8192, cnt, xwh, n, gT,
                                           bufBh, batch, pooledPart, F);
    k_gather<false><<<gW, BT, 0, stream>>>(xwh, meta, cnt, b3, x0h, n);

    // ---- pool(layer3) + head ----
    k_pool<<<PB, BT, 0, stream>>>(x0h, batch, n, pooledPart, 2 * F);
    k_head<<<NGRAPHS, FCAT, 0, stream>>>(pooledPart, batch, n, Wf, bf, out);
}

// Round 18
// 270.019 us; speedup vs baseline: 1.1285x; 1.0802x over previous
//
#include <hip/hip_runtime.h>
#include <hip/hip_bf16.h>
#include <hip/hip_fp16.h>
#include <math.h>

// ---------------------------------------------------------------------------
// GCN 3-layer + mean-pool + linear head + softmax, fp32 in/out.
// Padded-bucket adjacency (64 slots/node, no self slot). Pipeline:
//   k_zero:  cnt = 0
//   k_cfg1:  fused count+fill (ILP-4) ∥ layer-1 GEMM (LDS W1, unscaled)
//            ∥ Wt (W2,W3) fp16-transpose riders
//   k_gg:    gather layer k (4 nodes/wave, reg-hoisted meta) -> LDS tile ->
//            per-wave-quadrant MFMA for layer k+1 product (scaled store)
//   k_gather: layer-3 gather (1 node/wave) ∥ pool(layer2) rider
//   k_pool, k_head
// fp16 pipeline, MFMA v_mfma_f32_16x16x32_f16, fp32 accum.
// ---------------------------------------------------------------------------

#define F 64
#define NGRAPHS 128
#define NCLASSES 10
#define FCAT 192
#define PSPLIT 16
#define CAP 64
#define TPAD 72           // LDS tile row stride in halves (2-way banks = free)

typedef _Float16 f16x8 __attribute__((ext_vector_type(8)));
typedef float f32x4 __attribute__((ext_vector_type(4)));

// ---- cnt = 0 --------------------------------------------------------------
__global__ void k_zero(int* __restrict__ cnt, int n) {
    int i = blockIdx.x * blockDim.x + threadIdx.x;
    if (i < n) cnt[i] = 0;
}

// ---- fused count+fill (ILP-4) ∥ layer-1 GEMM (LDS W1) ∥ Wt riders ---------
__global__ __launch_bounds__(256) void k_cfg1(
        const int* __restrict__ row, const int* __restrict__ col,
        int* __restrict__ cnt, int* __restrict__ meta, int E,
        const float* __restrict__ W1, const float* __restrict__ W2,
        const float* __restrict__ W3, __half* __restrict__ Wt,
        const float* __restrict__ features,
        __half* __restrict__ xwh, int n, int cfB, int gT, int mx2) {
    if ((int)blockIdx.x >= mx2) {
        // Wt riders: convert W2,W3 -> Wt[4096..12287] ([w][c][k] fp16)
        int t = ((int)blockIdx.x - mx2) * 256 + threadIdx.x;
        if (t < 8192) {
            int w = t >> 12, idx = t & 4095;
            int c = idx >> 6, k = idx & 63;
            const float* W = (w == 0) ? W2 : W3;
            Wt[4096 + t] = __float2half(W[k * F + c]);
        }
        return;
    }
    int half = blockIdx.x >> 1;
    if ((blockIdx.x & 1) == 0) {
        if (half >= cfB) return;
        int e0 = (half * 256 + threadIdx.x) * 4;
        if (e0 + 3 < E) {
            int4 c4 = *(const int4*)(col + e0);
            int4 r4 = *(const int4*)(row + e0);
            int s0 = atomicAdd(&cnt[c4.x], 1);
            int s1 = atomicAdd(&cnt[c4.y], 1);
            int s2 = atomicAdd(&cnt[c4.z], 1);
            int s3 = atomicAdd(&cnt[c4.w], 1);
            meta[((size_t)c4.x << 6) + s0] = r4.x;
            meta[((size_t)c4.y << 6) + s1] = r4.y;
            meta[((size_t)c4.z << 6) + s2] = r4.z;
            meta[((size_t)c4.w << 6) + s3] = r4.w;
        } else {
            for (int e = e0; e < E; ++e) {
                int c = col[e];
                int s = atomicAdd(&cnt[c], 1);
                meta[((size_t)c << 6) + s] = row[e];
            }
        }
        return;
    }
    if (half >= gT) return;
    __shared__ __half Wl[64 * TPAD];
    for (int i = threadIdx.x; i < 4096; i += 256) {
        int k = i >> 6, c = i & 63;
        Wl[c * TPAD + k] = __float2half(W1[i]);
    }
    __syncthreads();
    int wid = (int)((half * 256 + threadIdx.x) >> 6);
    int lane = threadIdx.x & 63;
    int r0 = wid * 16;
    if (r0 >= n) return;
    int rA = min(r0 + (lane & 15), n - 1);
    int kOff = (lane >> 4) * 8;
    const float4* xp = (const float4*)(features + (size_t)rA * F + kOff);
    float4 fa = xp[0], fb = xp[1];
    float4 fc = xp[8], fd = xp[9];
    f16x8 a0 = {(_Float16)fa.x, (_Float16)fa.y, (_Float16)fa.z, (_Float16)fa.w,
                (_Float16)fb.x, (_Float16)fb.y, (_Float16)fb.z, (_Float16)fb.w};
    f16x8 a1 = {(_Float16)fc.x, (_Float16)fc.y, (_Float16)fc.z, (_Float16)fc.w,
                (_Float16)fd.x, (_Float16)fd.y, (_Float16)fd.z, (_Float16)fd.w};
    f32x4 acc0, acc1, acc2, acc3;
#define DO_CT(CT, ACC) { \
        const __half* bb = Wl + ((CT) * 16 + (lane & 15)) * TPAD + kOff; \
        f16x8 b0 = *(const f16x8*)bb; \
        f16x8 b1 = *(const f16x8*)(bb + 32); \
        f32x4 c = {0.f, 0.f, 0.f, 0.f}; \
        c = __builtin_amdgcn_mfma_f32_16x16x32_f16(a0, b0, c, 0, 0, 0); \
        c = __builtin_amdgcn_mfma_f32_16x16x32_f16(a1, b1, c, 0, 0, 0); \
        ACC = c; }
    DO_CT(0, acc0) DO_CT(1, acc1) DO_CT(2, acc2) DO_CT(3, acc3)
#undef DO_CT
    int rBase = r0 + ((lane >> 4) << 2);
    int cl = lane & 15;
#define ST_CT(CT, ACC) { \
        __half* op = xwh + (size_t)rBase * F + (CT) * 16 + cl; \
        if (rBase + 0 < n) op[0 * F] = __float2half(ACC.x); \
        if (rBase + 1 < n) op[1 * F] = __float2half(ACC.y); \
        if (rBase + 2 < n) op[2 * F] = __float2half(ACC.z); \
        if (rBase + 3 < n) op[3 * F] = __float2half(ACC.w); }
    ST_CT(0, acc0) ST_CT(1, acc1) ST_CT(2, acc2) ST_CT(3, acc3)
#undef ST_CT
}

// ---- fused gather(layer k) + gemm(layer k+1), optional pool rider ---------
// Block = 16 nodes. Each wave gathers 4 nodes -> LDS tile + buf; sync; each
// wave computes col-quadrant waveId of the 16-row MFMA tile (scaled store).
template<bool SCALE_SRC>
__global__ __launch_bounds__(256) void k_gg(
        const __half* __restrict__ xwin, const int* __restrict__ meta,
        const int* __restrict__ cnt, const float* __restrict__ bias,
        __half* __restrict__ bufOut, const __half* __restrict__ Wtn,
        __half* __restrict__ xwout, int n, int ggB,
        const __half* __restrict__ poolSrc, const int* __restrict__ batch,
        float* __restrict__ pooledPart, int layerOff) {
    __shared__ float red[256];
    __shared__ __half tile[16 * TPAD];
    if ((int)blockIdx.x >= ggB) {
        int b = blockIdx.x - ggB;
        int g = b >> 4, part = b & 15;
        int lo = 0, hi = n;
        while (lo < hi) { int m = (lo + hi) >> 1; if (batch[m] < g) lo = m + 1; else hi = m; }
        int s0 = lo;
        lo = s0; hi = n;
        while (lo < hi) { int m = (lo + hi) >> 1; if (batch[m] < g + 1) lo = m + 1; else hi = m; }
        int e0 = lo;
        int len = e0 - s0;
        int chunk = (len + PSPLIT - 1) / PSPLIT;
        int r0 = s0 + part * chunk;
        int r1 = min(r0 + chunk, e0);
        int f = threadIdx.x & 63, sub = threadIdx.x >> 6;
        float s = 0.0f;
        for (int i = r0 + sub; i < r1; i += 4)
            s += __half2float(poolSrc[(size_t)i * F + f]);
        red[threadIdx.x] = s;
        __syncthreads();
        if (threadIdx.x < 64) {
            float t = red[f] + red[f + 64] + red[f + 128] + red[f + 192];
            pooledPart[(size_t)(part * NGRAPHS + g) * FCAT + layerOff + f] = t;
        }
        return;
    }
    int waveId = threadIdx.x >> 6;
    int lane = threadIdx.x & 63;
    int g = lane >> 3, s = lane & 7;
    int tbase = blockIdx.x * 16;
    for (int q = 0; q < 4; ++q) {
        int idx = tbase + waveId * 4 + q;
        int v = min(idx, n - 1);
        int deg = cnt[v];
        float dc = rsqrtf((float)(deg + 1));
        size_t mbase = (size_t)v << 6;
        int myMeta = (lane < deg) ? meta[mbase + lane] : 0;
        float myDr = 0.0f;
        if (SCALE_SRC) myDr = (lane < deg) ? rsqrtf((float)(cnt[myMeta] + 1)) : 0.0f;
        float a0 = 0.f, a1 = 0.f, a2 = 0.f, a3 = 0.f;
        float a4 = 0.f, a5 = 0.f, a6 = 0.f, a7 = 0.f;
        if (g == 0) {
            uint4 v4 = *((const uint4*)(xwin + mbase) + s);
            __half2 h0 = *reinterpret_cast<const __half2*>(&v4.x);
            __half2 h1 = *reinterpret_cast<const __half2*>(&v4.y);
            __half2 h2 = *reinterpret_cast<const __half2*>(&v4.z);
            __half2 h3 = *reinterpret_cast<const __half2*>(&v4.w);
            float w = SCALE_SRC ? dc : 1.0f;
            float2 f;
            f = __half22float2(h0); a0 = f.x * w; a1 = f.y * w;
            f = __half22float2(h1); a2 = f.x * w; a3 = f.y * w;
            f = __half22float2(h2); a4 = f.x * w; a5 = f.y * w;
            f = __half22float2(h3); a6 = f.x * w; a7 = f.y * w;
        }
        for (int i = g; i < deg; i += 8) {
            int r = __shfl(myMeta, i);
            uint4 v4 = *((const uint4*)(xwin + ((size_t)r << 6)) + s);
            __half2 h0 = *reinterpret_cast<const __half2*>(&v4.x);
            __half2 h1 = *reinterpret_cast<const __half2*>(&v4.y);
            __half2 h2 = *reinterpret_cast<const __half2*>(&v4.z);
            __half2 h3 = *reinterpret_cast<const __half2*>(&v4.w);
            float2 f;
            if (SCALE_SRC) {
                float dr = __shfl(myDr, i);
                f = __half22float2(h0); a0 = fmaf(f.x, dr, a0); a1 = fmaf(f.y, dr, a1);
                f = __half22float2(h1); a2 = fmaf(f.x, dr, a2); a3 = fmaf(f.y, dr, a3);
                f = __half22float2(h2); a4 = fmaf(f.x, dr, a4); a5 = fmaf(f.y, dr, a5);
                f = __half22float2(h3); a6 = fmaf(f.x, dr, a6); a7 = fmaf(f.y, dr, a7);
            } else {
                f = __half22float2(h0); a0 += f.x; a1 += f.y;
                f = __half22float2(h1); a2 += f.x; a3 += f.y;
                f = __half22float2(h2); a4 += f.x; a5 += f.y;
                f = __half22float2(h3); a6 += f.x; a7 += f.y;
            }
        }
#pragma unroll
        for (int m = 8; m <= 32; m <<= 1) {
            a0 += __shfl_xor(a0, m); a1 += __shfl_xor(a1, m);
            a2 += __shfl_xor(a2, m); a3 += __shfl_xor(a3, m);
            a4 += __shfl_xor(a4, m); a5 += __shfl_xor(a5, m);
            a6 += __shfl_xor(a6, m); a7 += __shfl_xor(a7, m);
        }
        if (g == 0) {
            float4 bv0 = ((const float4*)bias)[2 * s];
            float4 bv1 = ((const float4*)bias)[2 * s + 1];
            __half2 o0 = __floats2half2_rn(fmaxf(fmaf(a0, dc, bv0.x), 0.f),
                                           fmaxf(fmaf(a1, dc, bv0.y), 0.f));
            __half2 o1 = __floats2half2_rn(fmaxf(fmaf(a2, dc, bv0.z), 0.f),
                                           fmaxf(fmaf(a3, dc, bv0.w), 0.f));
            __half2 o2 = __floats2half2_rn(fmaxf(fmaf(a4, dc, bv1.x), 0.f),
                                           fmaxf(fmaf(a5, dc, bv1.y), 0.f));
            __half2 o3 = __floats2half2_rn(fmaxf(fmaf(a6, dc, bv1.z), 0.f),
                                           fmaxf(fmaf(a7, dc, bv1.w), 0.f));
            uint4 pk;
            pk.x = *reinterpret_cast<unsigned int*>(&o0);
            pk.y = *reinterpret_cast<unsigned int*>(&o1);
            pk.z = *reinterpret_cast<unsigned int*>(&o2);
            pk.w = *reinterpret_cast<unsigned int*>(&o3);
            *(uint4*)&tile[(waveId * 4 + q) * TPAD + s * 8] = pk;
            if (idx < n) *((uint4*)(bufOut + mbase) + s) = pk;
        }
    }
    __syncthreads();
    // ---- gemm quadrant waveId of this 16-row tile ----
    int ar = lane & 15;
    int kOff = (lane >> 4) * 8;
    const __half* abase = tile + ar * TPAD + kOff;
    f16x8 a0 = *(const f16x8*)abase;
    f16x8 a1 = *(const f16x8*)(abase + 32);
    const f16x8* bp = (const f16x8*)(Wtn + ((waveId * 16 + ar) << 6) + kOff);
    f16x8 b0 = bp[0], b1 = bp[4];
    f32x4 c = {0.f, 0.f, 0.f, 0.f};
    c = __builtin_amdgcn_mfma_f32_16x16x32_f16(a0, b0, c, 0, 0, 0);
    c = __builtin_amdgcn_mfma_f32_16x16x32_f16(a1, b1, c, 0, 0, 0);
    int rBase = tbase + ((lane >> 4) << 2);
    int q0 = min(rBase + 0, n - 1), q1 = min(rBase + 1, n - 1);
    int q2 = min(rBase + 2, n - 1), q3 = min(rBase + 3, n - 1);
    float d0 = rsqrtf((float)(cnt[q0] + 1));
    float d1 = rsqrtf((float)(cnt[q1] + 1));
    float d2 = rsqrtf((float)(cnt[q2] + 1));
    float d3 = rsqrtf((float)(cnt[q3] + 1));
    __half* op = xwout + (size_t)rBase * F + waveId * 16 + ar;
    if (rBase + 0 < n) op[0 * F] = __float2half(c.x * d0);
    if (rBase + 1 < n) op[1 * F] = __float2half(c.y * d1);
    if (rBase + 2 < n) op[2 * F] = __float2half(c.z * d2);
    if (rBase + 3 < n) op[3 * F] = __float2half(c.w * d3);
}

// ---- layer-3 gather (1 node/wave) ∥ pool rider ----------------------------
__global__ __launch_bounds__(256) void k_gather(
        const __half* __restrict__ xwh, const int* __restrict__ meta,
        const int* __restrict__ cnt, const float* __restrict__ bias,
        __half* __restrict__ out, int n, int gatherBlocks,
        const __half* __restrict__ poolSrc, const int* __restrict__ batch,
        float* __restrict__ pooledPart, int layerOff) {
    if ((int)blockIdx.x >= gatherBlocks) {
        __shared__ float red[256];
        int b = blockIdx.x - gatherBlocks;
        int g = b >> 4, part = b & 15;
        int lo = 0, hi = n;
        while (lo < hi) { int m = (lo + hi) >> 1; if (batch[m] < g) lo = m + 1; else hi = m; }
        int s0 = lo;
        lo = s0; hi = n;
        while (lo < hi) { int m = (lo + hi) >> 1; if (batch[m] < g + 1) lo = m + 1; else hi = m; }
        int e0 = lo;
        int len = e0 - s0;
        int chunk = (len + PSPLIT - 1) / PSPLIT;
        int r0 = s0 + part * chunk;
        int r1 = min(r0 + chunk, e0);
        int f = threadIdx.x & 63, sub = threadIdx.x >> 6;
        float s = 0.0f;
        for (int i = r0 + sub; i < r1; i += 4)
            s += __half2float(poolSrc[(size_t)i * F + f]);
        red[threadIdx.x] = s;
        __syncthreads();
        if (threadIdx.x < 64) {
            float t = red[f] + red[f + 64] + red[f + 128] + red[f + 192];
            pooledPart[(size_t)(part * NGRAPHS + g) * FCAT + layerOff + f] = t;
        }
        return;
    }
    int wid = (int)((blockIdx.x * blockDim.x + threadIdx.x) >> 6);
    if (wid >= n) return;
    int lane = threadIdx.x & 63;
    int g = lane >> 3, s = lane & 7;
    int deg = cnt[wid];
    float dc = rsqrtf((float)(deg + 1));
    size_t mbase = (size_t)wid << 6;
    int myMeta = (lane < deg) ? meta[mbase + lane] : 0;
    float a0 = 0.f, a1 = 0.f, a2 = 0.f, a3 = 0.f;
    float a4 = 0.f, a5 = 0.f, a6 = 0.f, a7 = 0.f;
    if (g == 0) {
        uint4 v = *((const uint4*)(xwh + mbase) + s);
        __half2 h0 = *reinterpret_cast<const __half2*>(&v.x);
        __half2 h1 = *reinterpret_cast<const __half2*>(&v.y);
        __half2 h2 = *reinterpret_cast<const __half2*>(&v.z);
        __half2 h3 = *reinterpret_cast<const __half2*>(&v.w);
        float2 f;
        f = __half22float2(h0); a0 = f.x; a1 = f.y;
        f = __half22float2(h1); a2 = f.x; a3 = f.y;
        f = __half22float2(h2); a4 = f.x; a5 = f.y;
        f = __half22float2(h3); a6 = f.x; a7 = f.y;
    }
    for (int i = g; i < deg; i += 8) {
        int r = __shfl(myMeta, i);
        uint4 v = *((const uint4*)(xwh + ((size_t)r << 6)) + s);
        __half2 h0 = *reinterpret_cast<const __half2*>(&v.x);
        __half2 h1 = *reinterpret_cast<const __half2*>(&v.y);
        __half2 h2 = *reinterpret_cast<const __half2*>(&v.z);
        __half2 h3 = *reinterpret_cast<const __half2*>(&v.w);
        float2 f;
        f = __half22float2(h0); a0 += f.x; a1 += f.y;
        f = __half22float2(h1); a2 += f.x; a3 += f.y;
        f = __half22float2(h2); a4 += f.x; a5 += f.y;
        f = __half22float2(h3); a6 += f.x; a7 += f.y;
    }
#pragma unroll
    for (int m = 8; m <= 32; m <<= 1) {
        a0 += __shfl_xor(a0, m); a1 += __shfl_xor(a1, m);
        a2 += __shfl_xor(a2, m); a3 += __shfl_xor(a3, m);
        a4 += __shfl_xor(a4, m); a5 += __shfl_xor(a5, m);
        a6 += __shfl_xor(a6, m); a7 += __shfl_xor(a7, m);
    }
    if (g == 0) {
        float4 bv0 = ((const float4*)bias)[2 * s];
        float4 bv1 = ((const float4*)bias)[2 * s + 1];
        __half2 o0 = __floats2half2_rn(fmaxf(fmaf(a0, dc, bv0.x), 0.f),
                                       fmaxf(fmaf(a1, dc, bv0.y), 0.f));
        __half2 o1 = __floats2half2_rn(fmaxf(fmaf(a2, dc, bv0.z), 0.f),
                                       fmaxf(fmaf(a3, dc, bv0.w), 0.f));
        __half2 o2 = __floats2half2_rn(fmaxf(fmaf(a4, dc, bv1.x), 0.f),
                                       fmaxf(fmaf(a5, dc, bv1.y), 0.f));
        __half2 o3 = __floats2half2_rn(fmaxf(fmaf(a6, dc, bv1.z), 0.f),
                                       fmaxf(fmaf(a7, dc, bv1.w), 0.f));
        uint4 pk;
        pk.x = *reinterpret_cast<unsigned int*>(&o0);
        pk.y = *reinterpret_cast<unsigned int*>(&o1);
        pk.z = *reinterpret_cast<unsigned int*>(&o2);
        pk.w = *reinterpret_cast<unsigned int*>(&o3);
        *((uint4*)(out + mbase) + s) = pk;
    }
}

// ---- standalone pool (layer 3) --------------------------------------------
__global__ __launch_bounds__(256) void k_pool(const __half* __restrict__ src,
                                              const int* __restrict__ batch, int n,
                                              float* __restrict__ pooledPart,
                                              int layerOff) {
    int g = blockIdx.x >> 4, part = blockIdx.x & 15;
    int lo = 0, hi = n;
    while (lo < hi) { int m = (lo + hi) >> 1; if (batch[m] < g) lo = m + 1; else hi = m; }
    int s0 = lo;
    lo = s0; hi = n;
    while (lo < hi) { int m = (lo + hi) >> 1; if (batch[m] < g + 1) lo = m + 1; else hi = m; }
    int e0 = lo;
    int len = e0 - s0;
    int chunk = (len + PSPLIT - 1) / PSPLIT;
    int r0 = s0 + part * chunk;
    int r1 = min(r0 + chunk, e0);
    __shared__ float red[256];
    int f = threadIdx.x & 63, sub = threadIdx.x >> 6;
    float s = 0.0f;
    for (int i = r0 + sub; i < r1; i += 4)
        s += __half2float(src[(size_t)i * F + f]);
    red[threadIdx.x] = s;
    __syncthreads();
    if (threadIdx.x < 64) {
        float t = red[f] + red[f + 64] + red[f + 128] + red[f + 192];
        pooledPart[(size_t)(part * NGRAPHS + g) * FCAT + layerOff + f] = t;
    }
}

// one block per graph: reduce 16 partials -> pooled (LDS), logits, softmax
__global__ __launch_bounds__(192) void k_head(const float* __restrict__ pooledPart,
                                              const int* __restrict__ batch, int n,
                                              const float* __restrict__ Wf,
                                              const float* __restrict__ bf,
                                              float* __restrict__ out) {
    int g = blockIdx.x;
    __shared__ float pool[FCAT];
    __shared__ float lg[NCLASSES];
    int f = threadIdx.x;
    float s = 0.0f;
#pragma unroll
    for (int p = 0; p < PSPLIT; ++p)
        s += pooledPart[(size_t)(p * NGRAPHS + g) * FCAT + f];
    int lo = 0, hi = n;
    while (lo < hi) { int m = (lo + hi) >> 1; if (batch[m] < g) lo = m + 1; else hi = m; }
    int s0 = lo;
    lo = s0; hi = n;
    while (lo < hi) { int m = (lo + hi) >> 1; if (batch[m] < g + 1) lo = m + 1; else hi = m; }
    float invc = 1.0f / fmaxf((float)(lo - s0), 1.0f);
    pool[f] = s * invc;
    __syncthreads();
    if (f < NCLASSES) {
        float acc = bf[f];
        for (int k = 0; k < FCAT; ++k) acc = fmaf(pool[k], Wf[k * NCLASSES + f], acc);
        lg[f] = acc;
    }
    __syncthreads();
    if (f == 0) {
        float mx = lg[0];
#pragma unroll
        for (int c = 1; c < NCLASSES; ++c) mx = fmaxf(mx, lg[c]);
        float ss = 0.0f;
        float e[NCLASSES];
#pragma unroll
        for (int c = 0; c < NCLASSES; ++c) { e[c] = expf(lg[c] - mx); ss += e[c]; }
        float inv = 1.0f / ss;
#pragma unroll
        for (int c = 0; c < NCLASSES; ++c) out[g * NCLASSES + c] = e[c] * inv;
    }
}

// ---------------------------------------------------------------------------

extern "C" void kernel_launch(void* const* d_in, const int* in_sizes, int n_in,
                              void* d_out, int out_size, void* d_ws, size_t ws_size,
                              hipStream_t stream) {
    const float* features = (const float*)d_in[0];
    const int*   edge     = (const int*)d_in[1];
    const int*   batch    = (const int*)d_in[2];
    const float* W1 = (const float*)d_in[3]; const float* b1 = (const float*)d_in[4];
    const float* W2 = (const float*)d_in[5]; const float* b2 = (const float*)d_in[6];
    const float* W3 = (const float*)d_in[7]; const float* b3 = (const float*)d_in[8];
    const float* Wf = (const float*)d_in[9]; const float* bf = (const float*)d_in[10];
    float* out = (float*)d_out;

    const int n = in_sizes[0] / F;   // 100000
    const int E = in_sizes[1] / 2;   // 1600000
    const int* row = edge;
    const int* col = edge + E;

    // workspace layout
    __half* x0h   = (__half*)d_ws;                     // [n*64] layer3 out
    __half* bufAh = x0h + (size_t)n * F;               // [n*64] layer1 out
    __half* bufBh = bufAh + (size_t)n * F;             // [n*64] layer2 out
    __half* xwA   = bufBh + (size_t)n * F;             // [n*64] product buf A
    __half* xwB   = xwA + (size_t)n * F;               // [n*64] product buf B
    __half* Wt    = xwB + (size_t)n * F;               // [3*64*64]
    int*    meta  = (int*)(Wt + 3 * F * F);            // [n*CAP]
    int*    cnt   = meta + (size_t)n * CAP;            // [n]
    float*  pooledPart = (float*)(cnt + n);            // [16*128*192]

    const int BT = 256;
    int cfB = (E + 1023) / 1024;           // count+fill blocks (4 edges/thread)
    int gT  = ((n + 15) / 16 + 3) / 4;     // layer-1 gemm blocks
    int mx2 = 2 * max(cfB, gT);
    int ggB = (n + 15) / 16;               // fused gather+gemm blocks (6250)
    int gW  = (n + 3) / 4;                 // plain gather blocks (25000)
    const int PB = NGRAPHS * PSPLIT;       // 2048 pool blocks

    // ---- build ----
    k_zero<<<(n + BT - 1) / BT, BT, 0, stream>>>(cnt, n);
    k_cfg1<<<mx2 + 32, BT, 0, stream>>>(row, col, cnt, meta, E, W1, W2, W3, Wt,
                                        features, xwA, n, cfB, gT, mx2);

    // ---- gather1 + gemm2 (xwA -> bufA, bufA-tile @ W2 -> xwB) ----
    k_gg<true><<<ggB, BT, 0, stream>>>(xwA, meta, cnt, b1, bufAh, Wt + 4096,
                                       xwB, n, ggB, nullptr, batch, pooledPart, 0);
    // ---- gather2 + gemm3 ∥ pool(layer1) ----
    k_gg<false><<<ggB + PB, BT, 0, stream>>>(xwB, meta, cnt, b2, bufBh, Wt + 8192,
                                             xwA, n, ggB, bufAh, batch, pooledPart, 0);
    // ---- gather3 ∥ pool(layer2) ----
    k_gather<<<gW + PB, BT, 0, stream>>>(xwA, meta, cnt, b3, x0h, n, gW,
                                         bufBh, batch, pooledPart, F);

    // ---- pool(layer3) + head ----
    k_pool<<<PB, BT, 0, stream>>>(x0h, batch, n, pooledPart, 2 * F);
    k_head<<<NGRAPHS, FCAT, 0, stream>>>(pooledPart, batch, n, Wf, bf, out);
}